// Round 2
// baseline (263.634 us; speedup 1.0000x reference)
//
#include <hip/hip_runtime.h>
#include <hip/hip_bf16.h>

#define GSZ 36
static const int NX  = 16 * 32 * 224 * 224;     // 25,690,112
static const int NX4 = NX / 4;                  // 6,422,528 (NX % 4 == 0)
static const int NW  = 32 * 32 * 3 * 3;         // 9,216
static const int GXN = (NX + GSZ - 1) / GSZ;    // 713,615
static const int HWp = 224 * 224;               // 50,176

typedef short bf16x8 __attribute__((ext_vector_type(8)));
typedef float f32x4  __attribute__((ext_vector_type(4)));

// floor(n/36), exact for n < 2^31
__device__ __forceinline__ unsigned div36(unsigned n) {
    return (unsigned)(((unsigned long long)n * 954437177ull) >> 35);
}
// scale = 2^(floor(log2 m) - 7) via exponent field (m normal > 0)
__device__ __forceinline__ float scale_from_max(float m) {
    int e = (int)((__float_as_uint(m) >> 23) & 0xffu) - 127;
    return __uint_as_float((unsigned)(e + 120) << 23);
}
// 1/scale for power-of-two scale: bits = 0x7F000000 - scale_bits
__device__ __forceinline__ float inv_from_scale(float s) {
    return __uint_as_float(0x7F000000u - __float_as_uint(s));
}
__device__ __forceinline__ unsigned short f2bf(float f) {
    return (unsigned short)(__float_as_uint(f) >> 16);  // exact for BFP-8 values
}

// ---------- quantize w + layout to wt[s][co][ci] bf16 ----------
__global__ void k_quant_wt(const float* __restrict__ w, unsigned short* __restrict__ wt) {
    int g = threadIdx.x;            // 1 block, 256 threads = 256 groups exactly
    int base = g * GSZ;
    float v[GSZ];
    const float4* p = reinterpret_cast<const float4*>(w + base);
    #pragma unroll
    for (int i = 0; i < 9; ++i) {
        float4 t = p[i];
        v[4*i+0] = t.x; v[4*i+1] = t.y; v[4*i+2] = t.z; v[4*i+3] = t.w;
    }
    float m = 0.0f;
    #pragma unroll
    for (int i = 0; i < GSZ; ++i) m = fmaxf(m, fabsf(v[i]));
    if (m > 0.0f) {
        float s = scale_from_max(m), inv = inv_from_scale(s);
        #pragma unroll
        for (int i = 0; i < GSZ; ++i) v[i] = rintf(v[i] * inv) * s;
    }
    #pragma unroll
    for (int i = 0; i < GSZ; ++i) {
        int f = base + i;
        int co = f / 288, rem = f - co * 288;
        int ci = rem / 9, s = rem - ci * 9;
        wt[s * 1024 + co * 32 + ci] = f2bf(v[i]);
    }
}

// ---------- fused x: BFP-quantize (flat-36 groups) + NCHW->NHWC, one pass ----------
// Thread-owns-group. Each of 448 tasks = (ci, gi) owns one full 36-elem flat group:
// 9 float4 global loads into regs, in-register maxabs, quantize from regs,
// predicated uint2 bf16 writes of the in-tile chunks. No LDS atomics, no scale
// arrays, no second global pass, single barrier before the transpose.
#define TSTR 452   // bf16 tile row stride (bank-spread, keeps uint2 writes 8B-aligned)
__global__ __launch_bounds__(256, 4) void k_quant_x_fused(const float* __restrict__ x,
                                                          unsigned short* __restrict__ xt) {
    __shared__ unsigned short tile[32 * TSTR];   // 28,928 B quantized bf16 tile

    int t = threadIdx.x;
    int b = blockIdx.y, hp = blockIdx.x;
    int F0 = (b * 32) * HWp + hp * 448;

    #pragma unroll
    for (int it = 0; it < 2; ++it) {
        int task = t + 256 * it;
        if (task < 448) {
            int ci = (task * 2341) >> 15;              // task / 14, exact for task < 448
            int gi = task - ci * 14;
            int F = F0 + ci * HWp;
            int r = F - 36 * (int)div36((unsigned)F);  // F % 36 (always a multiple of 4)
            int rel0 = 36 * gi - r;                    // tile-relative start of this group
            if (rel0 < 448) {                          // group overlaps the 448-px tile span
                int g4 = (int)(((unsigned)(F - r)) >> 2) + 9 * gi;  // float4 idx of group base
                f32x4 v[9];
                #pragma unroll
                for (int i = 0; i < 9; ++i) {
                    f32x4 tv = {0.f, 0.f, 0.f, 0.f};
                    int f4 = g4 + i;
                    if ((unsigned)f4 < (unsigned)NX4)
                        tv = reinterpret_cast<const f32x4*>(x)[f4];
                    v[i] = tv;
                }
                float m = 0.f;
                #pragma unroll
                for (int i = 0; i < 9; ++i)
                    #pragma unroll
                    for (int k = 0; k < 4; ++k) m = fmaxf(m, fabsf(v[i][k]));
                if (m > 0.f) {
                    float s = scale_from_max(m), inv = inv_from_scale(s);
                    #pragma unroll
                    for (int i = 0; i < 9; ++i)
                        #pragma unroll
                        for (int k = 0; k < 4; ++k)
                            v[i][k] = rintf(v[i][k] * inv) * s;
                }
                #pragma unroll
                for (int i = 0; i < 9; ++i) {
                    int rel = rel0 + 4 * i;            // multiple of 4; chunk fully in or out
                    if ((unsigned)rel < 448u) {
                        uint2 o;
                        o.x = (unsigned)f2bf(v[i][0]) | ((unsigned)f2bf(v[i][1]) << 16);
                        o.y = (unsigned)f2bf(v[i][2]) | ((unsigned)f2bf(v[i][3]) << 16);
                        *reinterpret_cast<uint2*>(&tile[ci * TSTR + rel]) = o;
                    }
                }
            }
        }
    }
    __syncthreads();

    // Phase D: gather 8 ci per pixel, coalesced 16B NHWC stores
    unsigned short* ob = xt + ((size_t)b * HWp + hp * 448) * 32;
    for (int j = 0; j < 7; ++j) {
        int qd = t + 256 * j;                      // 1792 16B-chunks
        int px = qd >> 2;
        int c0 = (qd & 3) * 8;
        unsigned uu[4];
        #pragma unroll
        for (int p = 0; p < 4; ++p) {
            unsigned short lo = tile[(c0 + 2 * p) * TSTR + px];
            unsigned short hi = tile[(c0 + 2 * p + 1) * TSTR + px];
            uu[p] = (unsigned)lo | ((unsigned)hi << 16);
        }
        *reinterpret_cast<uint4*>(ob + (size_t)px * 32 + c0) =
            make_uint4(uu[0], uu[1], uu[2], uu[3]);
    }
}

// ---------- MFMA conv: 3x3 SAME as 9 shifted K=32 GEMMs, coalesced epilogue ----------
// mfma(A=w_frag[m=co], B=x_frag[n=px]) -> D row=co, col=px. Each scalar f32
// store instruction covers 4 x 64B full segments (lanes 0..15 = consecutive px).
#define PXS 40
__global__ __launch_bounds__(256, 2) void k_conv_mfma(const unsigned short* __restrict__ xt,
                                                      const unsigned short* __restrict__ wt,
                                                      const float* __restrict__ bias,
                                                      float* __restrict__ out) {
    __shared__ __align__(16) unsigned short xs[18 * 34 * PXS];  // 48,960 B

    int tid  = threadIdx.x;
    int lane = tid & 63;
    int wid  = tid >> 6;
    int b  = blockIdx.z;
    int h0 = blockIdx.y * 16;
    int w0 = blockIdx.x * 32;

    // stage 18x34 halo (all 32 ci) from NHWC
    const unsigned short* xb = xt + (size_t)b * HWp * 32;
    #pragma unroll
    for (int k = 0; k < 10; ++k) {
        int q = tid + k * 256;
        if (q < 2448) {                       // 18*34*4 16B-chunks
            int r = q / 136;
            int rem = q - r * 136;
            int p = rem >> 2, ch = rem & 3;
            int gh = h0 + r - 1, gw = w0 + p - 1;
            uint4 val = make_uint4(0u, 0u, 0u, 0u);
            if ((unsigned)gh < 224u && (unsigned)gw < 224u)
                val = *reinterpret_cast<const uint4*>(xb + ((size_t)(gh * 224 + gw)) * 32 + ch * 8);
            *reinterpret_cast<uint4*>(&xs[(r * 34 + p) * PXS + ch * 8]) = val;
        }
    }

    // weight fragments (A-operand: m=lane&15=co, k=(lane>>4)*8+j=ci)
    bf16x8 Wf[9][2];
    #pragma unroll
    for (int s = 0; s < 9; ++s)
        #pragma unroll
        for (int hf = 0; hf < 2; ++hf)
            Wf[s][hf] = *reinterpret_cast<const bf16x8*>(
                wt + s * 1024 + (hf * 16 + (lane & 15)) * 32 + (lane >> 4) * 8);

    // acc init = bias; D row = co = (lane>>4)*4 + reg (+16*hf)
    int m4 = (lane >> 4) << 2;
    f32x4 acc[8][2];
    {
        f32x4 b0, b1;
        #pragma unroll
        for (int r = 0; r < 4; ++r) {
            b0[r] = bias[m4 + r];
            b1[r] = bias[16 + m4 + r];
        }
        #pragma unroll
        for (int g = 0; g < 8; ++g) { acc[g][0] = b0; acc[g][1] = b1; }
    }

    __syncthreads();

    int row4 = wid << 2;
    int kchunk = (lane >> 4) << 3;
    #pragma unroll
    for (int s = 0; s < 9; ++s) {
        int kh = s / 3, kw = s - kh * 3;
        #pragma unroll
        for (int g = 0; g < 8; ++g) {
            int row = row4 + (g >> 1);
            int col = ((g & 1) << 4) + (lane & 15);
            bf16x8 X = *reinterpret_cast<const bf16x8*>(
                &xs[((row + kh) * 34 + col + kw) * PXS + kchunk]);
            acc[g][0] = __builtin_amdgcn_mfma_f32_16x16x32_bf16(Wf[s][0], X, acc[g][0], 0, 0, 0);
            acc[g][1] = __builtin_amdgcn_mfma_f32_16x16x32_bf16(Wf[s][1], X, acc[g][1], 0, 0, 0);
        }
    }

    // epilogue: col = lane&15 = px, row = m4 + reg = co -> line-coalesced stores
    int pxl = lane & 15;
    #pragma unroll
    for (int g = 0; g < 8; ++g) {
        int h = h0 + row4 + (g >> 1);
        int wl = w0 + ((g & 1) << 4) + pxl;
        size_t base = (size_t)(b * 32) * HWp + h * 224 + wl;
        #pragma unroll
        for (int hf = 0; hf < 2; ++hf)
            #pragma unroll
            for (int r = 0; r < 4; ++r)
                out[base + (size_t)((hf << 4) + m4 + r) * HWp] = acc[g][hf][r];
    }
}

// ---------- out-quant, in place, wave-cooperative (coalesced 16B ld/st) ----------
__global__ __launch_bounds__(256, 4) void k_quant_out(float* __restrict__ buf) {
    __shared__ float lds[4 * 2304];              // 36,864 B (wave: 64 groups = 2304 f32)
    int t = threadIdx.x, lane = t & 63, wid = t >> 6;
    int gbase = (blockIdx.x * 4 + wid) * 64;
    int f4base = gbase * 9;                      // gbase*36/4

    #pragma unroll
    for (int i = 0; i < 9; ++i) {
        int f4 = f4base + i * 64 + lane;
        float4 v = make_float4(0.f, 0.f, 0.f, 0.f);
        if ((unsigned)f4 < (unsigned)NX4) v = reinterpret_cast<const float4*>(buf)[f4];
        *reinterpret_cast<float4*>(&lds[wid * 2304 + (i * 64 + lane) * 4]) = v;
    }
    __syncthreads();

    if (gbase + lane < GXN) {
        float* p = &lds[wid * 2304 + lane * 36];    // byte 144*lane: 16B-aligned
        f32x4 vv[9];
        #pragma unroll
        for (int i = 0; i < 9; ++i) vv[i] = *reinterpret_cast<f32x4*>(p + 4 * i);
        float m = 0.f;
        #pragma unroll
        for (int i = 0; i < 9; ++i)
            #pragma unroll
            for (int k = 0; k < 4; ++k) m = fmaxf(m, fabsf(vv[i][k]));
        if (m > 0.f) {                               // guard: all-zero group stays zero
            float s = scale_from_max(m), inv = inv_from_scale(s);
            #pragma unroll
            for (int i = 0; i < 9; ++i) {
                #pragma unroll
                for (int k = 0; k < 4; ++k) vv[i][k] = rintf(vv[i][k] * inv) * s;
                *reinterpret_cast<f32x4*>(p + 4 * i) = vv[i];
            }
        }
    }
    __syncthreads();

    #pragma unroll
    for (int i = 0; i < 9; ++i) {
        int f4 = f4base + i * 64 + lane;
        if ((unsigned)f4 < (unsigned)NX4)
            reinterpret_cast<float4*>(buf)[f4] =
                *reinterpret_cast<float4*>(&lds[wid * 2304 + (i * 64 + lane) * 4]);
    }
}

extern "C" void kernel_launch(void* const* d_in, const int* in_sizes, int n_in,
                              void* d_out, int out_size, void* d_ws, size_t ws_size,
                              hipStream_t stream) {
    (void)in_sizes; (void)n_in; (void)out_size; (void)ws_size;
    const float* x    = (const float*)d_in[0];
    const float* w    = (const float*)d_in[1];
    const float* bias = (const float*)d_in[2];
    float* out        = (float*)d_out;

    unsigned short* xt = (unsigned short*)d_ws;   // NX bf16 NHWC (51.4 MB)
    unsigned short* wt = xt + NX;                 // 9,216 bf16

    k_quant_wt<<<1, 256, 0, stream>>>(w, wt);
    k_quant_x_fused<<<dim3(112, 16), 256, 0, stream>>>(x, xt);
    k_conv_mfma<<<dim3(7, 14, 16), 256, 0, stream>>>(xt, wt, bias, out);
    // 2788 blocks: ceil(ceil(713615/64)/4)
    k_quant_out<<<2788, 256, 0, stream>>>(out);
}

// Round 3
// 247.398 us; speedup vs baseline: 1.0656x; 1.0656x over previous
//
#include <hip/hip_runtime.h>
#include <hip/hip_bf16.h>

#define GSZ 36
static const int NX  = 16 * 32 * 224 * 224;     // 25,690,112
static const int NX4 = NX / 4;                  // 6,422,528 (NX % 4 == 0)
static const int NW  = 32 * 32 * 3 * 3;         // 9,216
static const int GXN = (NX + GSZ - 1) / GSZ;    // 713,615
static const int HWp = 224 * 224;               // 50,176

typedef short bf16x8 __attribute__((ext_vector_type(8)));
typedef float f32x4  __attribute__((ext_vector_type(4)));

// floor(n/36), exact for n < 2^31
__device__ __forceinline__ unsigned div36(unsigned n) {
    return (unsigned)(((unsigned long long)n * 954437177ull) >> 35);
}
// scale = 2^(floor(log2 m) - 7) via exponent field (m normal > 0)
__device__ __forceinline__ float scale_from_max(float m) {
    int e = (int)((__float_as_uint(m) >> 23) & 0xffu) - 127;
    return __uint_as_float((unsigned)(e + 120) << 23);
}
// 1/scale for power-of-two scale: bits = 0x7F000000 - scale_bits
__device__ __forceinline__ float inv_from_scale(float s) {
    return __uint_as_float(0x7F000000u - __float_as_uint(s));
}
__device__ __forceinline__ unsigned short f2bf(float f) {
    return (unsigned short)(__float_as_uint(f) >> 16);  // exact for BFP-8 values
}

// ---------- quantize w + layout to wt[s][co][ci] bf16 ----------
__global__ void k_quant_wt(const float* __restrict__ w, unsigned short* __restrict__ wt) {
    int g = threadIdx.x;            // 1 block, 256 threads = 256 groups exactly
    int base = g * GSZ;
    float v[GSZ];
    const float4* p = reinterpret_cast<const float4*>(w + base);
    #pragma unroll
    for (int i = 0; i < 9; ++i) {
        float4 t = p[i];
        v[4*i+0] = t.x; v[4*i+1] = t.y; v[4*i+2] = t.z; v[4*i+3] = t.w;
    }
    float m = 0.0f;
    #pragma unroll
    for (int i = 0; i < GSZ; ++i) m = fmaxf(m, fabsf(v[i]));
    if (m > 0.0f) {
        float s = scale_from_max(m), inv = inv_from_scale(s);
        #pragma unroll
        for (int i = 0; i < GSZ; ++i) v[i] = rintf(v[i] * inv) * s;
    }
    #pragma unroll
    for (int i = 0; i < GSZ; ++i) {
        int f = base + i;
        int co = f / 288, rem = f - co * 288;
        int ci = rem / 9, s = rem - ci * 9;
        wt[s * 1024 + co * 32 + ci] = f2bf(v[i]);
    }
}

// ---------- fused x: BFP-quantize (flat-36 groups) + NCHW->NHWC, one pass ----------
// Round 5: coalesced cover loads held in REGISTERS (16 f32x4/thread), per-float4
// partial max -> private LDS slot (no atomics: groups are float4-aligned since
// 36 = 9*4 and all group starts are 4-aligned), 448 group-tasks reduce 9 partials
// -> scale, then quantize from regs. One global pass, no atomics. pmax unions
// with the bf16 tile (disjoint lifetimes across a barrier).
#define TSTR 452   // bf16 tile row stride (bank-spread, keeps uint2 writes 8B-aligned)
__global__ __launch_bounds__(256, 4) void k_quant_x_fused(const float* __restrict__ x,
                                                          unsigned short* __restrict__ xt) {
    __shared__ __align__(16) unsigned char raw[32 * TSTR * 2];   // 28,928 B
    unsigned short* tile = reinterpret_cast<unsigned short*>(raw);   // phase C/D
    float* pmax = reinterpret_cast<float*>(raw);                     // phase A/B (16,384 B)
    __shared__ float scl[32 * 14];                                   // 1,792 B

    int t = threadIdx.x;
    int b = blockIdx.y, hp = blockIdx.x;
    int F0 = (b * 32) * HWp + hp * 448;

    int c4  = t & 127;          // float4 index within the 128-float4 cover
    int ciB = t >> 7;           // 0 or 1; thread's ci set = {ciB + 2j}

    // Phase A: coalesced group-aligned cover loads into regs; partial max -> LDS
    f32x4 v[16];
    #pragma unroll
    for (int j = 0; j < 16; ++j) {
        int ci = ciB + 2 * j;
        int F = F0 + ci * HWp;
        int r = F - 36 * (int)div36((unsigned)F);            // F % 36 (multiple of 4)
        int f4 = (int)(((unsigned)(F - r)) >> 2) + c4;       // cover float4 index
        f32x4 tv = {0.f, 0.f, 0.f, 0.f};
        if ((unsigned)f4 < (unsigned)NX4)
            tv = reinterpret_cast<const f32x4*>(x)[f4];
        v[j] = tv;
        pmax[ci * 128 + c4] = fmaxf(fmaxf(fabsf(tv[0]), fabsf(tv[1])),
                                    fmaxf(fabsf(tv[2]), fabsf(tv[3])));
    }
    __syncthreads();

    // Phase B: group max = max of 9 consecutive partials -> scale (0 = all-zero group)
    #pragma unroll
    for (int it = 0; it < 2; ++it) {
        int task = t + 256 * it;
        if (task < 448) {
            int ci = (task * 2341) >> 15;                    // task / 14, exact
            int gi = task - ci * 14;
            const float* pp = &pmax[ci * 128 + 9 * gi];
            float m = pp[0];
            #pragma unroll
            for (int i = 1; i < 9; ++i) m = fmaxf(m, pp[i]);
            scl[task] = (m > 0.f) ? scale_from_max(m) : 0.f;
        }
    }
    __syncthreads();

    // Phase C: quantize held regs, pack bf16 into tile (overwrites pmax region)
    int gi4 = (c4 * 57) >> 9;                                // c4 / 9, exact for c4 < 128
    #pragma unroll
    for (int j = 0; j < 16; ++j) {
        int ci = ciB + 2 * j;
        int F = F0 + ci * HWp;
        int r = F - 36 * (int)div36((unsigned)F);
        int rel = 4 * c4 - r;                                // tile-relative elem offset
        if ((unsigned)rel < 448u) {
            float s = scl[ci * 14 + gi4];
            f32x4 q = v[j];
            if (s > 0.f) {
                float inv = inv_from_scale(s);
                #pragma unroll
                for (int k = 0; k < 4; ++k) q[k] = rintf(q[k] * inv) * s;
            } else {
                q = f32x4{0.f, 0.f, 0.f, 0.f};
            }
            uint2 o;
            o.x = (unsigned)f2bf(q[0]) | ((unsigned)f2bf(q[1]) << 16);
            o.y = (unsigned)f2bf(q[2]) | ((unsigned)f2bf(q[3]) << 16);
            *reinterpret_cast<uint2*>(&tile[ci * TSTR + rel]) = o;
        }
    }
    __syncthreads();

    // Phase D: gather 8 ci per pixel, coalesced 16B NHWC stores
    unsigned short* ob = xt + ((size_t)b * HWp + hp * 448) * 32;
    for (int j = 0; j < 7; ++j) {
        int qd = t + 256 * j;                      // 1792 16B-chunks
        int px = qd >> 2;
        int c0 = (qd & 3) * 8;
        unsigned uu[4];
        #pragma unroll
        for (int p = 0; p < 4; ++p) {
            unsigned short lo = tile[(c0 + 2 * p) * TSTR + px];
            unsigned short hi = tile[(c0 + 2 * p + 1) * TSTR + px];
            uu[p] = (unsigned)lo | ((unsigned)hi << 16);
        }
        *reinterpret_cast<uint4*>(ob + (size_t)px * 32 + c0) =
            make_uint4(uu[0], uu[1], uu[2], uu[3]);
    }
}

// ---------- MFMA conv: 3x3 SAME as 9 shifted K=32 GEMMs, coalesced epilogue ----------
// mfma(A=w_frag[m=co], B=x_frag[n=px]) -> D row=co, col=px. Each scalar f32
// store instruction covers 4 x 64B full segments (lanes 0..15 = consecutive px).
#define PXS 40
__global__ __launch_bounds__(256, 2) void k_conv_mfma(const unsigned short* __restrict__ xt,
                                                      const unsigned short* __restrict__ wt,
                                                      const float* __restrict__ bias,
                                                      float* __restrict__ out) {
    __shared__ __align__(16) unsigned short xs[18 * 34 * PXS];  // 48,960 B

    int tid  = threadIdx.x;
    int lane = tid & 63;
    int wid  = tid >> 6;
    int b  = blockIdx.z;
    int h0 = blockIdx.y * 16;
    int w0 = blockIdx.x * 32;

    // stage 18x34 halo (all 32 ci) from NHWC
    const unsigned short* xb = xt + (size_t)b * HWp * 32;
    #pragma unroll
    for (int k = 0; k < 10; ++k) {
        int q = tid + k * 256;
        if (q < 2448) {                       // 18*34*4 16B-chunks
            int r = q / 136;
            int rem = q - r * 136;
            int p = rem >> 2, ch = rem & 3;
            int gh = h0 + r - 1, gw = w0 + p - 1;
            uint4 val = make_uint4(0u, 0u, 0u, 0u);
            if ((unsigned)gh < 224u && (unsigned)gw < 224u)
                val = *reinterpret_cast<const uint4*>(xb + ((size_t)(gh * 224 + gw)) * 32 + ch * 8);
            *reinterpret_cast<uint4*>(&xs[(r * 34 + p) * PXS + ch * 8]) = val;
        }
    }

    // weight fragments (A-operand: m=lane&15=co, k=(lane>>4)*8+j=ci)
    bf16x8 Wf[9][2];
    #pragma unroll
    for (int s = 0; s < 9; ++s)
        #pragma unroll
        for (int hf = 0; hf < 2; ++hf)
            Wf[s][hf] = *reinterpret_cast<const bf16x8*>(
                wt + s * 1024 + (hf * 16 + (lane & 15)) * 32 + (lane >> 4) * 8);

    // acc init = bias; D row = co = (lane>>4)*4 + reg (+16*hf)
    int m4 = (lane >> 4) << 2;
    f32x4 acc[8][2];
    {
        f32x4 b0, b1;
        #pragma unroll
        for (int r = 0; r < 4; ++r) {
            b0[r] = bias[m4 + r];
            b1[r] = bias[16 + m4 + r];
        }
        #pragma unroll
        for (int g = 0; g < 8; ++g) { acc[g][0] = b0; acc[g][1] = b1; }
    }

    __syncthreads();

    int row4 = wid << 2;
    int kchunk = (lane >> 4) << 3;
    #pragma unroll
    for (int s = 0; s < 9; ++s) {
        int kh = s / 3, kw = s - kh * 3;
        #pragma unroll
        for (int g = 0; g < 8; ++g) {
            int row = row4 + (g >> 1);
            int col = ((g & 1) << 4) + (lane & 15);
            bf16x8 X = *reinterpret_cast<const bf16x8*>(
                &xs[((row + kh) * 34 + col + kw) * PXS + kchunk]);
            acc[g][0] = __builtin_amdgcn_mfma_f32_16x16x32_bf16(Wf[s][0], X, acc[g][0], 0, 0, 0);
            acc[g][1] = __builtin_amdgcn_mfma_f32_16x16x32_bf16(Wf[s][1], X, acc[g][1], 0, 0, 0);
        }
    }

    // epilogue: col = lane&15 = px, row = m4 + reg = co -> line-coalesced stores
    int pxl = lane & 15;
    #pragma unroll
    for (int g = 0; g < 8; ++g) {
        int h = h0 + row4 + (g >> 1);
        int wl = w0 + ((g & 1) << 4) + pxl;
        size_t base = (size_t)(b * 32) * HWp + h * 224 + wl;
        #pragma unroll
        for (int hf = 0; hf < 2; ++hf)
            #pragma unroll
            for (int r = 0; r < 4; ++r)
                out[base + (size_t)((hf << 4) + m4 + r) * HWp] = acc[g][hf][r];
    }
}

// ---------- out-quant, in place, wave-cooperative (coalesced 16B ld/st) ----------
__global__ __launch_bounds__(256, 4) void k_quant_out(float* __restrict__ buf) {
    __shared__ float lds[4 * 2304];              // 36,864 B (wave: 64 groups = 2304 f32)
    int t = threadIdx.x, lane = t & 63, wid = t >> 6;
    int gbase = (blockIdx.x * 4 + wid) * 64;
    int f4base = gbase * 9;                      // gbase*36/4

    #pragma unroll
    for (int i = 0; i < 9; ++i) {
        int f4 = f4base + i * 64 + lane;
        float4 v = make_float4(0.f, 0.f, 0.f, 0.f);
        if ((unsigned)f4 < (unsigned)NX4) v = reinterpret_cast<const float4*>(buf)[f4];
        *reinterpret_cast<float4*>(&lds[wid * 2304 + (i * 64 + lane) * 4]) = v;
    }
    __syncthreads();

    if (gbase + lane < GXN) {
        float* p = &lds[wid * 2304 + lane * 36];    // byte 144*lane: 16B-aligned
        f32x4 vv[9];
        #pragma unroll
        for (int i = 0; i < 9; ++i) vv[i] = *reinterpret_cast<f32x4*>(p + 4 * i);
        float m = 0.f;
        #pragma unroll
        for (int i = 0; i < 9; ++i)
            #pragma unroll
            for (int k = 0; k < 4; ++k) m = fmaxf(m, fabsf(vv[i][k]));
        if (m > 0.f) {                               // guard: all-zero group stays zero
            float s = scale_from_max(m), inv = inv_from_scale(s);
            #pragma unroll
            for (int i = 0; i < 9; ++i) {
                #pragma unroll
                for (int k = 0; k < 4; ++k) vv[i][k] = rintf(vv[i][k] * inv) * s;
                *reinterpret_cast<f32x4*>(p + 4 * i) = vv[i];
            }
        }
    }
    __syncthreads();

    #pragma unroll
    for (int i = 0; i < 9; ++i) {
        int f4 = f4base + i * 64 + lane;
        if ((unsigned)f4 < (unsigned)NX4)
            reinterpret_cast<float4*>(buf)[f4] =
                *reinterpret_cast<float4*>(&lds[wid * 2304 + (i * 64 + lane) * 4]);
    }
}

extern "C" void kernel_launch(void* const* d_in, const int* in_sizes, int n_in,
                              void* d_out, int out_size, void* d_ws, size_t ws_size,
                              hipStream_t stream) {
    (void)in_sizes; (void)n_in; (void)out_size; (void)ws_size;
    const float* x    = (const float*)d_in[0];
    const float* w    = (const float*)d_in[1];
    const float* bias = (const float*)d_in[2];
    float* out        = (float*)d_out;

    unsigned short* xt = (unsigned short*)d_ws;   // NX bf16 NHWC (51.4 MB)
    unsigned short* wt = xt + NX;                 // 9,216 bf16

    k_quant_wt<<<1, 256, 0, stream>>>(w, wt);
    k_quant_x_fused<<<dim3(112, 16), 256, 0, stream>>>(x, xt);
    k_conv_mfma<<<dim3(7, 14, 16), 256, 0, stream>>>(xt, wt, bias, out);
    // 2788 blocks: ceil(ceil(713615/64)/4)
    k_quant_out<<<2788, 256, 0, stream>>>(out);
}

// Round 4
// 246.894 us; speedup vs baseline: 1.0678x; 1.0020x over previous
//
#include <hip/hip_runtime.h>
#include <hip/hip_bf16.h>

#define GSZ 36
static const int NX  = 16 * 32 * 224 * 224;     // 25,690,112
static const int NX4 = NX / 4;                  // 6,422,528 (NX % 4 == 0)
static const int NW  = 32 * 32 * 3 * 3;         // 9,216
static const int GXN = (NX + GSZ - 1) / GSZ;    // 713,615
static const int HWp = 224 * 224;               // 50,176

typedef short bf16x8 __attribute__((ext_vector_type(8)));
typedef float f32x4  __attribute__((ext_vector_type(4)));

// floor(n/36), exact for n < 2^31
__device__ __forceinline__ unsigned div36(unsigned n) {
    return (unsigned)(((unsigned long long)n * 954437177ull) >> 35);
}
// scale = 2^(floor(log2 m) - 7) via exponent field (m normal > 0)
__device__ __forceinline__ float scale_from_max(float m) {
    int e = (int)((__float_as_uint(m) >> 23) & 0xffu) - 127;
    return __uint_as_float((unsigned)(e + 120) << 23);
}
// 1/scale for power-of-two scale: bits = 0x7F000000 - scale_bits
__device__ __forceinline__ float inv_from_scale(float s) {
    return __uint_as_float(0x7F000000u - __float_as_uint(s));
}
__device__ __forceinline__ unsigned short f2bf(float f) {
    return (unsigned short)(__float_as_uint(f) >> 16);  // exact for BFP-8 values
}

// ---------- quantize w + layout to wt[s][co][ci] bf16 ----------
__global__ void k_quant_wt(const float* __restrict__ w, unsigned short* __restrict__ wt) {
    int g = threadIdx.x;            // 1 block, 256 threads = 256 groups exactly
    int base = g * GSZ;
    float v[GSZ];
    const float4* p = reinterpret_cast<const float4*>(w + base);
    #pragma unroll
    for (int i = 0; i < 9; ++i) {
        float4 t = p[i];
        v[4*i+0] = t.x; v[4*i+1] = t.y; v[4*i+2] = t.z; v[4*i+3] = t.w;
    }
    float m = 0.0f;
    #pragma unroll
    for (int i = 0; i < GSZ; ++i) m = fmaxf(m, fabsf(v[i]));
    if (m > 0.0f) {
        float s = scale_from_max(m), inv = inv_from_scale(s);
        #pragma unroll
        for (int i = 0; i < GSZ; ++i) v[i] = rintf(v[i] * inv) * s;
    }
    #pragma unroll
    for (int i = 0; i < GSZ; ++i) {
        int f = base + i;
        int co = f / 288, rem = f - co * 288;
        int ci = rem / 9, s = rem - ci * 9;
        wt[s * 1024 + co * 32 + ci] = f2bf(v[i]);
    }
}

// ---------- fused x: BFP-quantize (flat-36 groups) + NCHW->NHWC, one pass ----------
// Coalesced cover loads held in REGISTERS (16 f32x4/thread), per-float4 partial
// max -> private LDS slot (no atomics: groups are float4-aligned since 36 = 9*4
// and all group starts are 4-aligned), 448 group-tasks reduce 9 partials ->
// scale, then quantize from regs. One global pass, no atomics.
#define TSTR 452   // bf16 tile row stride (bank-spread, keeps uint2 writes 8B-aligned)
__global__ __launch_bounds__(256, 4) void k_quant_x_fused(const float* __restrict__ x,
                                                          unsigned short* __restrict__ xt) {
    __shared__ __align__(16) unsigned char raw[32 * TSTR * 2];   // 28,928 B
    unsigned short* tile = reinterpret_cast<unsigned short*>(raw);   // phase C/D
    float* pmax = reinterpret_cast<float*>(raw);                     // phase A/B (16,384 B)
    __shared__ float scl[32 * 14];                                   // 1,792 B

    int t = threadIdx.x;
    int b = blockIdx.y, hp = blockIdx.x;
    int F0 = (b * 32) * HWp + hp * 448;

    int c4  = t & 127;          // float4 index within the 128-float4 cover
    int ciB = t >> 7;           // 0 or 1; thread's ci set = {ciB + 2j}

    // Phase A: coalesced group-aligned cover loads into regs; partial max -> LDS
    f32x4 v[16];
    #pragma unroll
    for (int j = 0; j < 16; ++j) {
        int ci = ciB + 2 * j;
        int F = F0 + ci * HWp;
        int r = F - 36 * (int)div36((unsigned)F);            // F % 36 (multiple of 4)
        int f4 = (int)(((unsigned)(F - r)) >> 2) + c4;       // cover float4 index
        f32x4 tv = {0.f, 0.f, 0.f, 0.f};
        if ((unsigned)f4 < (unsigned)NX4)
            tv = reinterpret_cast<const f32x4*>(x)[f4];
        v[j] = tv;
        pmax[ci * 128 + c4] = fmaxf(fmaxf(fabsf(tv[0]), fabsf(tv[1])),
                                    fmaxf(fabsf(tv[2]), fabsf(tv[3])));
    }
    __syncthreads();

    // Phase B: group max = max of 9 consecutive partials -> scale (0 = all-zero group)
    #pragma unroll
    for (int it = 0; it < 2; ++it) {
        int task = t + 256 * it;
        if (task < 448) {
            int ci = (task * 2341) >> 15;                    // task / 14, exact
            int gi = task - ci * 14;
            const float* pp = &pmax[ci * 128 + 9 * gi];
            float m = pp[0];
            #pragma unroll
            for (int i = 1; i < 9; ++i) m = fmaxf(m, pp[i]);
            scl[task] = (m > 0.f) ? scale_from_max(m) : 0.f;
        }
    }
    __syncthreads();

    // Phase C: quantize held regs, pack bf16 into tile (overwrites pmax region)
    int gi4 = (c4 * 57) >> 9;                                // c4 / 9, exact for c4 < 128
    #pragma unroll
    for (int j = 0; j < 16; ++j) {
        int ci = ciB + 2 * j;
        int F = F0 + ci * HWp;
        int r = F - 36 * (int)div36((unsigned)F);
        int rel = 4 * c4 - r;                                // tile-relative elem offset
        if ((unsigned)rel < 448u) {
            float s = scl[ci * 14 + gi4];
            f32x4 q = v[j];
            if (s > 0.f) {
                float inv = inv_from_scale(s);
                #pragma unroll
                for (int k = 0; k < 4; ++k) q[k] = rintf(q[k] * inv) * s;
            } else {
                q = f32x4{0.f, 0.f, 0.f, 0.f};
            }
            uint2 o;
            o.x = (unsigned)f2bf(q[0]) | ((unsigned)f2bf(q[1]) << 16);
            o.y = (unsigned)f2bf(q[2]) | ((unsigned)f2bf(q[3]) << 16);
            *reinterpret_cast<uint2*>(&tile[ci * TSTR + rel]) = o;
        }
    }
    __syncthreads();

    // Phase D: gather 8 ci per pixel, coalesced 16B NHWC stores
    unsigned short* ob = xt + ((size_t)b * HWp + hp * 448) * 32;
    for (int j = 0; j < 7; ++j) {
        int qd = t + 256 * j;                      // 1792 16B-chunks
        int px = qd >> 2;
        int c0 = (qd & 3) * 8;
        unsigned uu[4];
        #pragma unroll
        for (int p = 0; p < 4; ++p) {
            unsigned short lo = tile[(c0 + 2 * p) * TSTR + px];
            unsigned short hi = tile[(c0 + 2 * p + 1) * TSTR + px];
            uu[p] = (unsigned)lo | ((unsigned)hi << 16);
        }
        *reinterpret_cast<uint4*>(ob + (size_t)px * 32 + c0) =
            make_uint4(uu[0], uu[1], uu[2], uu[3]);
    }
}

// ---------- MFMA conv: 3x3 SAME as 9 shifted K=32 GEMMs, coalesced epilogue ----------
// mfma(A=w_frag[m=co], B=x_frag[n=px]) -> D row=co, col=px. Each scalar f32
// store instruction covers 4 x 64B full segments (lanes 0..15 = consecutive px).
#define PXS 40
__global__ __launch_bounds__(256, 2) void k_conv_mfma(const unsigned short* __restrict__ xt,
                                                      const unsigned short* __restrict__ wt,
                                                      const float* __restrict__ bias,
                                                      float* __restrict__ out) {
    __shared__ __align__(16) unsigned short xs[18 * 34 * PXS];  // 48,960 B

    int tid  = threadIdx.x;
    int lane = tid & 63;
    int wid  = tid >> 6;
    int b  = blockIdx.z;
    int h0 = blockIdx.y * 16;
    int w0 = blockIdx.x * 32;

    // stage 18x34 halo (all 32 ci) from NHWC
    const unsigned short* xb = xt + (size_t)b * HWp * 32;
    #pragma unroll
    for (int k = 0; k < 10; ++k) {
        int q = tid + k * 256;
        if (q < 2448) {                       // 18*34*4 16B-chunks
            int r = q / 136;
            int rem = q - r * 136;
            int p = rem >> 2, ch = rem & 3;
            int gh = h0 + r - 1, gw = w0 + p - 1;
            uint4 val = make_uint4(0u, 0u, 0u, 0u);
            if ((unsigned)gh < 224u && (unsigned)gw < 224u)
                val = *reinterpret_cast<const uint4*>(xb + ((size_t)(gh * 224 + gw)) * 32 + ch * 8);
            *reinterpret_cast<uint4*>(&xs[(r * 34 + p) * PXS + ch * 8]) = val;
        }
    }

    // weight fragments (A-operand: m=lane&15=co, k=(lane>>4)*8+j=ci)
    bf16x8 Wf[9][2];
    #pragma unroll
    for (int s = 0; s < 9; ++s)
        #pragma unroll
        for (int hf = 0; hf < 2; ++hf)
            Wf[s][hf] = *reinterpret_cast<const bf16x8*>(
                wt + s * 1024 + (hf * 16 + (lane & 15)) * 32 + (lane >> 4) * 8);

    // acc init = bias; D row = co = (lane>>4)*4 + reg (+16*hf)
    int m4 = (lane >> 4) << 2;
    f32x4 acc[8][2];
    {
        f32x4 b0, b1;
        #pragma unroll
        for (int r = 0; r < 4; ++r) {
            b0[r] = bias[m4 + r];
            b1[r] = bias[16 + m4 + r];
        }
        #pragma unroll
        for (int g = 0; g < 8; ++g) { acc[g][0] = b0; acc[g][1] = b1; }
    }

    __syncthreads();

    int row4 = wid << 2;
    int kchunk = (lane >> 4) << 3;
    #pragma unroll
    for (int s = 0; s < 9; ++s) {
        int kh = s / 3, kw = s - kh * 3;
        #pragma unroll
        for (int g = 0; g < 8; ++g) {
            int row = row4 + (g >> 1);
            int col = ((g & 1) << 4) + (lane & 15);
            bf16x8 X = *reinterpret_cast<const bf16x8*>(
                &xs[((row + kh) * 34 + col + kw) * PXS + kchunk]);
            acc[g][0] = __builtin_amdgcn_mfma_f32_16x16x32_bf16(Wf[s][0], X, acc[g][0], 0, 0, 0);
            acc[g][1] = __builtin_amdgcn_mfma_f32_16x16x32_bf16(Wf[s][1], X, acc[g][1], 0, 0, 0);
        }
    }

    // epilogue: col = lane&15 = px, row = m4 + reg = co -> line-coalesced stores
    int pxl = lane & 15;
    #pragma unroll
    for (int g = 0; g < 8; ++g) {
        int h = h0 + row4 + (g >> 1);
        int wl = w0 + ((g & 1) << 4) + pxl;
        size_t base = (size_t)(b * 32) * HWp + h * 224 + wl;
        #pragma unroll
        for (int hf = 0; hf < 2; ++hf)
            #pragma unroll
            for (int r = 0; r < 4; ++r)
                out[base + (size_t)((hf << 4) + m4 + r) * HWp] = acc[g][hf][r];
    }
}

// ---------- out-quant, in place: LDS-free 9-lane-set shuffle reduction ----------
// 9 lanes own one 36-elem group (9 float4). Lanes 0..62 of a wave cover 7 whole
// groups; the 63 float4 loads are contiguous -> fully coalesced. Group max via
// 4 rotate-max shuffle steps (rot 1,2,4,8 mod 9: window doubling covers 9).
// No LDS, no barriers, streaming at full occupancy.
#define QOG 112   // groups per wave (7 groups/iter * 16 iters)
__global__ __launch_bounds__(256) void k_quant_out(float* __restrict__ buf) {
    int t = threadIdx.x, lane = t & 63, wid = t >> 6;
    int s9 = (lane * 57) >> 9;          // lane / 9, exact for lane < 64
    int p9 = lane - s9 * 9;
    bool active = lane < 63;

    // per-thread-constant shuffle source lanes: rotate within the 9-lane set
    int src[4];
    #pragma unroll
    for (int k = 0; k < 4; ++k) {
        int rot = 1 << k;               // 1, 2, 4, 8
        int pp = p9 + rot; if (pp >= 9) pp -= 9;
        src[k] = active ? (s9 * 9 + pp) : 63;
    }

    int wave_g = (blockIdx.x * 4 + wid) * QOG;     // first group of this wave
    #pragma unroll 4
    for (int i = 0; i < 16; ++i) {
        int f4 = (wave_g + 7 * i) * 9 + lane;      // contiguous across lanes 0..62
        bool ld = active && (unsigned)f4 < (unsigned)NX4;
        f32x4 v = {0.f, 0.f, 0.f, 0.f};
        if (ld) v = reinterpret_cast<const f32x4*>(buf)[f4];
        float m = fmaxf(fmaxf(fabsf(v[0]), fabsf(v[1])),
                        fmaxf(fabsf(v[2]), fabsf(v[3])));
        #pragma unroll
        for (int k = 0; k < 4; ++k)
            m = fmaxf(m, __shfl(m, src[k]));
        if (m > 0.f) {
            float s = scale_from_max(m), inv = inv_from_scale(s);
            #pragma unroll
            for (int k = 0; k < 4; ++k) v[k] = rintf(v[k] * inv) * s;
        }
        if (ld) reinterpret_cast<f32x4*>(buf)[f4] = v;
    }
}

extern "C" void kernel_launch(void* const* d_in, const int* in_sizes, int n_in,
                              void* d_out, int out_size, void* d_ws, size_t ws_size,
                              hipStream_t stream) {
    (void)in_sizes; (void)n_in; (void)out_size; (void)ws_size;
    const float* x    = (const float*)d_in[0];
    const float* w    = (const float*)d_in[1];
    const float* bias = (const float*)d_in[2];
    float* out        = (float*)d_out;

    unsigned short* xt = (unsigned short*)d_ws;   // NX bf16 NHWC (51.4 MB)
    unsigned short* wt = xt + NX;                 // 9,216 bf16

    k_quant_wt<<<1, 256, 0, stream>>>(w, wt);
    k_quant_x_fused<<<dim3(112, 16), 256, 0, stream>>>(x, xt);
    k_conv_mfma<<<dim3(7, 14, 16), 256, 0, stream>>>(xt, wt, bias, out);
    // 1593 blocks: ceil(713615 / (4 waves * 112 groups))
    k_quant_out<<<1593, 256, 0, stream>>>(out);
}